// Round 12
// baseline (393.656 us; speedup 1.0000x reference)
//
#include <hip/hip_runtime.h>
#include <hip/hip_bf16.h>
#include <cmath>

// Problem constants
constexpr int Bc = 128, Tc = 128, Ac = 16;
constexpr int Dc = 256, Hc = 512, Qc = 128, QIc = 512, Vc = 64, NTk = 13;
// Masked logits: ref emits -inf; harness needs finite there.
constexpr float NEG_BIG = -1e30f;
// fp8 scaling: weights x16, activations x16 (exact pow2), acc x 1/256.
constexpr float ACT_SCALE = 16.f;
constexpr float ACC_SCALE = 1.f / 256.f;
constexpr float ACC_TO_ACT = 1.f / 16.f;  // ACC_SCALE*ACT_SCALE (epilogue fold)

typedef unsigned int uint;
typedef uint uint2v __attribute__((ext_vector_type(2)));
typedef uint uint4v __attribute__((ext_vector_type(4)));
typedef float f32x4 __attribute__((ext_vector_type(4)));

#define MFMA16F8(a, b, c) __builtin_amdgcn_mfma_f32_16x16x32_fp8_fp8(a, b, c, 0, 0, 0)

__device__ __forceinline__ long long mk_ll(uint lo, uint hi) {
  union { uint u[2]; long long l; } x;
  x.u[0] = lo; x.u[1] = hi;
  return x.l;
}
__device__ __forceinline__ unsigned short f2bfu(float f) {
  __hip_bfloat16 h = __float2bfloat16(f);
  return *(unsigned short*)&h;
}
__device__ __forceinline__ float bf2f(short s) {
  return __uint_as_float(((unsigned)(unsigned short)s) << 16);
}
__device__ __forceinline__ uint pack4_fp8(float a, float b, float c, float d) {
  uint v = 0;
  v = __builtin_amdgcn_cvt_pk_fp8_f32(a, b, v, 0);
  v = __builtin_amdgcn_cvt_pk_fp8_f32(c, d, v, 1);
  return v;
}

// ---------------------------------------------------------------------------
// Weight transform: fp32 [P][K][N] -> fp8 (x16) PAIRED MFMA fragments.
// Pair layout: frag[p][nt][kcp][lane] is 16 bytes:
//   bytes 0-7  = chunk kc=2kcp   (k = kc*32 + (lane>>4)*8 + j)
//   bytes 8-15 = chunk kc=2kcp+1
// One global_load_dwordx4 in the main loop feeds TWO MFMAs (r12: halves
// global-load instruction count). n = nt*16 + (lane&15).
// ---------------------------------------------------------------------------
__global__ void transform_all(const float* __restrict__ kW1, const float* __restrict__ kW2,
                              const float* __restrict__ kW3, const float* __restrict__ qW,
                              uint4v* __restrict__ kW1f, uint4v* __restrict__ kW2f,
                              uint4v* __restrict__ kW3f, uint4v* __restrict__ qWf) {
  int gid = blockIdx.x * 256 + threadIdx.x;
  const float* W;
  uint4v* dst;
  int NT, KCP, N, local;
  if (gid < 32768) {            // kW1: P4 x NT32 x KCP4
    W = kW1; dst = kW1f; NT = 32; KCP = 4; N = 512; local = gid;
  } else if (gid < 98304) {     // kW2: P4 x NT32 x KCP8
    W = kW2; dst = kW2f; NT = 32; KCP = 8; N = 512; local = gid - 32768;
  } else if (gid < 114688) {    // kW3: P4 x NT8 x KCP8
    W = kW3; dst = kW3f; NT = 8; KCP = 8; N = 128; local = gid - 98304;
  } else {                      // qW:  P4 x NT8 x KCP8
    W = qW; dst = qWf; NT = 8; KCP = 8; N = 128; local = gid - 114688;
  }
  int lane = local & 63;
  int frag = local >> 6;
  int kcp = frag % KCP;
  int rest = frag / KCP;
  int nt = rest % NT;
  int p = rest / NT;
  int K = KCP * 64;
  int n = nt * 16 + (lane & 15);
  int k0 = kcp * 64 + (lane >> 4) * 8;
  const float* src = W + ((size_t)p * K + k0) * N + n;
  float f[8], g[8];
#pragma unroll
  for (int j = 0; j < 8; ++j) {
    f[j] = src[(size_t)j * N] * ACT_SCALE;
    g[j] = src[(size_t)(j + 32) * N] * ACT_SCALE;
  }
  uint4v v;
  v.x = pack4_fp8(f[0], f[1], f[2], f[3]);
  v.y = pack4_fp8(f[4], f[5], f[6], f[7]);
  v.z = pack4_fp8(g[0], g[1], g[2], g[3]);
  v.w = pack4_fp8(g[4], g[5], g[6], g[7]);
  dst[local] = v;
}

// ---------------------------------------------------------------------------
// fp8 16x16x32 MFMA layer, paired-fragment variant (r12).
// Weights = A (WT outdim-tiles), activations = B (AT action-tiles), K = KC*32.
// Activation LDS layout is q-major: addr(row,kc,q) = row*SROW + q*QB + kc*8,
// QB = KC*8 -> a lane's consecutive kc fragments are contiguous, so ONE
// ds_read_b128 yields 2 kc-fragments (halves LDS read instrs vs r11).
// SROW ≡ 12 or 4 mod 32 dwords -> b128 bank starts tile at spacing 4 =
// wave64-b128 minimum aliasing.
// Weight loads: wave-uniform base + lane -> saddr global_load_dwordx4,
// 2 fragments per load.
// acc = WT*AT*4 regs; af = AT*4 + wv 4 + addr ~8 arch regs: fits 32/32 split
// of the 64-reg 8-wave/EU budget. #pragma unroll 1 (r7/r8: deeper = spill).
// C/D: lane holds action=lane&15, 4 consecutive outdims (4q+r) -> packed
// dword/b64/float4 epilogue stores.
// OUTMODE: 0 = fp8 x16 q-major hidden (OA=SROW_out, OB=QB_out),
//          1 = bf16 row-major KV (OA=stride in shorts),
//          2 = fp32 row-major QY, token rows only (OA=stride in floats).
// ---------------------------------------------------------------------------
template <int KC, int WT, int AT, bool RELU, int OUTMODE, int SROW, int QB, int OA, int OB>
__device__ __forceinline__ void layer16(
    const char* __restrict__ aB, void* __restrict__ o0,
    const uint4v* __restrict__ Wf, const float* __restrict__ bias,
    int wt0, int lane) {
  const int c = lane & 15, q = lane >> 4;
  const char* ap = aB + c * SROW + q * QB;
  constexpr int KCP = KC / 2;

  f32x4 acc[WT][AT];
#pragma unroll
  for (int wt = 0; wt < WT; ++wt)
#pragma unroll
    for (int at = 0; at < AT; ++at)
#pragma unroll
      for (int r = 0; r < 4; ++r) acc[wt][at][r] = 0.f;

#pragma unroll 1
  for (int kcp = 0; kcp < KCP; ++kcp) {
    uint4v af[AT];
#pragma unroll
    for (int at = 0; at < AT; ++at)
      af[at] = *(const uint4v*)(ap + at * 16 * SROW + kcp * 16);
#pragma unroll
    for (int wt = 0; wt < WT; ++wt) {
      // wave-uniform base + lane index -> saddr global load (no VALU addr math)
      const uint4v* wk = Wf + ((size_t)(wt0 + wt) * KCP + kcp) * 64;
      uint4v wv = wk[lane];
      long long wlo = mk_ll(wv.x, wv.y);
      long long whi = mk_ll(wv.z, wv.w);
#pragma unroll
      for (int at = 0; at < AT; ++at) {
        acc[wt][at] = MFMA16F8(wlo, mk_ll(af[at].x, af[at].y), acc[wt][at]);
        acc[wt][at] = MFMA16F8(whi, mk_ll(af[at].z, af[at].w), acc[wt][at]);
      }
    }
  }

#pragma unroll
  for (int wt = 0; wt < WT; ++wt) {
    const int nb = (wt0 + wt) * 16 + 4 * q;  // outdim base for this lane
    float4 bv = *(const float4*)(bias + nb);
#pragma unroll
    for (int at = 0; at < AT; ++at) {
      const int row = at * 16 + c;  // action row
      if (OUTMODE == 0) {
        float s0 = fmaf(acc[wt][at][0], ACC_TO_ACT, bv.x * ACT_SCALE);
        float s1 = fmaf(acc[wt][at][1], ACC_TO_ACT, bv.y * ACT_SCALE);
        float s2 = fmaf(acc[wt][at][2], ACC_TO_ACT, bv.z * ACT_SCALE);
        float s3 = fmaf(acc[wt][at][3], ACC_TO_ACT, bv.w * ACT_SCALE);
        if (RELU) {
          s0 = fmaxf(s0, 0.f); s1 = fmaxf(s1, 0.f);
          s2 = fmaxf(s2, 0.f); s3 = fmaxf(s3, 0.f);
        }
        // q-major out: outdim n -> (kco=n/32, qo=(n%32)/8, j=n%8); nb%8 in {0,4}
        const int kco = nb >> 5, qo = (nb & 31) >> 3, jo = nb & 7;
        *(uint*)((char*)o0 + row * OA + qo * OB + kco * 8 + jo) = pack4_fp8(s0, s1, s2, s3);
      } else if (OUTMODE == 1) {
        float s0 = fmaf(acc[wt][at][0], ACC_SCALE, bv.x);
        float s1 = fmaf(acc[wt][at][1], ACC_SCALE, bv.y);
        float s2 = fmaf(acc[wt][at][2], ACC_SCALE, bv.z);
        float s3 = fmaf(acc[wt][at][3], ACC_SCALE, bv.w);
        uint2v u;
        u.x = ((uint)f2bfu(s1) << 16) | f2bfu(s0);
        u.y = ((uint)f2bfu(s3) << 16) | f2bfu(s2);
        *(uint2v*)((short*)o0 + row * OA + nb) = u;
      } else {
        if (c < 4) {  // only real token rows
          float4 st;
          st.x = fmaf(acc[wt][at][0], ACC_SCALE, bv.x);
          st.y = fmaf(acc[wt][at][1], ACC_SCALE, bv.y);
          st.z = fmaf(acc[wt][at][2], ACC_SCALE, bv.z);
          st.w = fmaf(acc[wt][at][3], ACC_SCALE, bv.w);
          *(float4*)((float*)o0 + c * OA + nb) = st;
        }
      }
    }
  }
}

// ---------------------------------------------------------------------------
// Main fused kernel: 1024 threads (16 waves), 64 rows (4 tokens x 16 actions).
// 32arch+32acc regs -> 2 blocks x 16 waves = 32 waves/CU.
// phase = blockIdx&3 -> per-phase 512KB fp8 weight set stays L2-resident.
// LDS budget: bufA 35840 + bufB 35840 + beA 8960 + misc < 80KB (2 blocks/CU).
// ---------------------------------------------------------------------------
constexpr int QB_X = 64;     // Xs q-block (KC=8)
constexpr int SROW_X = 272;  // 68 dw == 4 mod 32 (b128 starts tile at spacing 4)
constexpr int QB_H = 128;    // H q-block (KC=16)
constexpr int SROW_H = 560;  // 140 dw == 12 mod 32
constexpr int SKV = 136;     // KV stride (bf16 elems)
constexpr int SQY = 132;     // QY stride (fp32 elems)

__global__ __launch_bounds__(1024, 8) void policy_main(
    const float* __restrict__ be, const int* __restrict__ va,
    const int* __restrict__ phase, const int* __restrict__ trick,
    const float* __restrict__ emb0, const float* __restrict__ emb1,
    const float* __restrict__ emb2, const float* __restrict__ ln_g,
    const float* __restrict__ ln_b,
    const float* __restrict__ kb1, const float* __restrict__ kb2,
    const float* __restrict__ kb3, const float* __restrict__ qb,
    const uint4v* __restrict__ kW1f, const uint4v* __restrict__ kW2f,
    const uint4v* __restrict__ kW3f, const uint4v* __restrict__ qWf,
    float* __restrict__ out) {
  __shared__ __align__(16) char bufA[64 * SROW_H];  // Xs [64][SROW_X] then H2 [64][SROW_H]
  __shared__ __align__(16) char bufB[64 * SROW_H];  // H1; then KV(17408)+QY(2112)
  __shared__ __align__(16) char beAb[16 * SROW_H];  // be tokens fp8 (rows 4..15 garbage)
  __shared__ float attn_s[64];
  __shared__ char inval_s[64];
  __shared__ int ph_s[4], tr_s[4];

  char* Xs = bufA;
  char* H2 = bufA;
  char* H1 = bufB;
  short* KV = (short*)bufB;                 // H1 dead after layer2
  float* QYs = (float*)(bufB + 64 * SKV * 2);  // after KV (17408)

  const int tid = threadIdx.x;
  const int w = tid >> 6, lane = tid & 63;
  const int p = blockIdx.x & 3;
  const int g = blockIdx.x >> 2;
  const int b = g >> 3;
  const int t0 = p * 32 + (g & 7) * 4;
  const int bt0 = b * Tc + t0;

  // ---- stage 0 (no internal barrier): masks, phase/trick, beA, LN->Xs ----
  if (tid < 64) {
    inval_s[tid] = (va[((size_t)bt0 * Ac + tid) * 3] == -1);
  } else if (tid < 68) {
    ph_s[tid - 64] = phase[bt0 + tid - 64];
  } else if (tid < 72) {
    tr_s[tid - 68] = trick[bt0 + tid - 68];
  }
  if (tid < 256) {  // beA rows 0..3 (x16 fp8), q-major slot (kc=(i)/4, q=i%4)
    int tok = tid >> 6, i = tid & 63;
    int kc = i >> 2, qq = i & 3;
    const float* bp = be + ((size_t)bt0 + tok) * QIc + kc * 32 + qq * 8;
    uint2v v8;
    v8.x = pack4_fp8(bp[0] * ACT_SCALE, bp[1] * ACT_SCALE, bp[2] * ACT_SCALE, bp[3] * ACT_SCALE);
    v8.y = pack4_fp8(bp[4] * ACT_SCALE, bp[5] * ACT_SCALE, bp[6] * ACT_SCALE, bp[7] * ACT_SCALE);
    *(uint2v*)(beAb + tok * SROW_H + qq * QB_H + kc * 8) = v8;
  }
  {
    // embed-sum + LayerNorm -> Xs fp8 x16 (16 thr/row x 16 dims), q-major store
    const int r = tid >> 4, part = tid & 15, d0 = part * 16;
    const int* vp = va + ((size_t)bt0 * Ac + r) * 3;
    int i0 = min(max(vp[0], 0), Vc - 1);
    int i1 = min(max(vp[1], 0), Vc - 1);
    int i2 = min(max(vp[2], 0), Vc - 1);
    const float4* e0 = (const float4*)(emb0 + i0 * Dc + d0);
    const float4* e1 = (const float4*)(emb1 + i1 * Dc + d0);
    const float4* e2 = (const float4*)(emb2 + i2 * Dc + d0);
    float xv[16];
    float sum = 0.f, ss = 0.f;
#pragma unroll
    for (int j = 0; j < 4; ++j) {
      float4 v0 = e0[j], v1 = e1[j], v2 = e2[j];
      float4 v;
      v.x = v0.x + v1.x + v2.x; v.y = v0.y + v1.y + v2.y;
      v.z = v0.z + v1.z + v2.z; v.w = v0.w + v1.w + v2.w;
      xv[j * 4 + 0] = v.x; xv[j * 4 + 1] = v.y; xv[j * 4 + 2] = v.z; xv[j * 4 + 3] = v.w;
      sum += v.x + v.y + v.z + v.w;
      ss += v.x * v.x + v.y * v.y + v.z * v.z + v.w * v.w;
    }
    sum += __shfl_xor(sum, 1); sum += __shfl_xor(sum, 2);
    sum += __shfl_xor(sum, 4); sum += __shfl_xor(sum, 8);
    ss += __shfl_xor(ss, 1);   ss += __shfl_xor(ss, 2);
    ss += __shfl_xor(ss, 4);   ss += __shfl_xor(ss, 8);
    const float mu = sum / (float)Dc;
    const float rstd = rsqrtf(ss / (float)Dc - mu * mu + 1e-5f);
    float y[16];
#pragma unroll
    for (int j = 0; j < 16; ++j) {
      int d = d0 + j;
      y[j] = ((xv[j] - mu) * rstd * ln_g[d] + ln_b[d]) * ACT_SCALE;
    }
    const int kc = part >> 1, q1 = (part & 1) * 2;
    uint2v v8;
    v8.x = pack4_fp8(y[0], y[1], y[2], y[3]);
    v8.y = pack4_fp8(y[4], y[5], y[6], y[7]);
    *(uint2v*)(Xs + r * SROW_X + q1 * QB_X + kc * 8) = v8;
    v8.x = pack4_fp8(y[8], y[9], y[10], y[11]);
    v8.y = pack4_fp8(y[12], y[13], y[14], y[15]);
    *(uint2v*)(Xs + r * SROW_X + (q1 + 1) * QB_X + kc * 8) = v8;
  }
  __syncthreads();

  // ---- layer1: X(64x256) @ kW1 -> H1(64x512) relu. 16 waves x 2wt x 4at ----
  layer16<8, 2, 4, true, 0, SROW_X, QB_X, SROW_H, QB_H>(
      Xs, H1, kW1f + (size_t)p * 8192, kb1 + p * Hc, w * 2, lane);
  __syncthreads();

  // ---- layer2: H1(64x512) @ kW2 -> H2(64x512) relu ----
  layer16<16, 2, 4, true, 0, SROW_H, QB_H, SROW_H, QB_H>(
      H1, H2, kW2f + (size_t)p * 16384, kb2 + p * Hc, w * 2, lane);
  __syncthreads();

  // ---- layer3 (waves 0-7) -> KV bf16; query (waves 8-15) -> QY fp32 ----
  if (w < 8) {
    layer16<16, 1, 4, false, 1, SROW_H, QB_H, SKV, 0>(
        H2, KV, kW3f + (size_t)p * 4096, kb3 + p * Qc, w, lane);
  } else {
    layer16<16, 1, 1, false, 2, SROW_H, QB_H, SQY, 0>(
        beAb, QYs, qWf + (size_t)p * 4096, qb + p * Qc, w - 8, lane);
  }
  __syncthreads();

  // ---- attn[r] = <QY[tok], KV[r]> / sqrt(Q) (16 thr/row x 8 dims) ----
  {
    const int r = tid >> 4, part = tid & 15, tok = r >> 4;
    const short* kp = KV + r * SKV + part * 8;
    const float* qp = QYs + tok * SQY + part * 8;
    float s = 0.f;
#pragma unroll
    for (int j = 0; j < 8; ++j) s += bf2f(kp[j]) * qp[j];
    s += __shfl_xor(s, 1); s += __shfl_xor(s, 2);
    s += __shfl_xor(s, 4); s += __shfl_xor(s, 8);
    if (part == 0) attn_s[r] = s * 0.08838834764831845f;  // 1/sqrt(128)
  }
  __syncthreads();

  // ---- mask, signal weight, log_softmax, store (one thread per token) ----
  if (tid < 4) {
    const int tok = tid;
    const int bt = bt0 + tok;
    float av[Ac];
    int nv = 0;
#pragma unroll
    for (int a = 0; a < Ac; ++a) {
      int iv = inval_s[tok * Ac + a];
      nv += iv ? 0 : 1;
      av[a] = iv ? NEG_BIG : attn_s[tok * Ac + a];
    }
    if (ph_s[tok] == 1) {
      const int nt = NTk - tr_s[tok];
      float dp = 1.f;
      for (int i = 0; i < nt; ++i) dp *= 0.6f;
      const float ps = 0.4f / (1.f - dp);
      float wgt = (nv == 1) ? 0.f : logf(fmaxf((1.f - ps) / ps * ((float)nv - 1.f), 1e-5f));
      av[0] += wgt;
    }
    float m = NEG_BIG;
#pragma unroll
    for (int a = 0; a < Ac; ++a) m = fmaxf(m, av[a]);
    float s = 0.f;
#pragma unroll
    for (int a = 0; a < Ac; ++a) s += expf(av[a] - m);
    const float lse = logf(s) + m;
#pragma unroll
    for (int a = 0; a < Ac; ++a)
      out[bt * Ac + a] = inval_s[tok * Ac + a] ? NEG_BIG : (av[a] - lse);
  }
}

extern "C" void kernel_launch(void* const* d_in, const int* in_sizes, int n_in,
                              void* d_out, int out_size, void* d_ws, size_t ws_size,
                              hipStream_t stream) {
  const float* be   = (const float*)d_in[0];
  const int*   va   = (const int*)d_in[1];
  const int*   ph   = (const int*)d_in[2];
  const int*   tr   = (const int*)d_in[3];
  const float* emb0 = (const float*)d_in[4];
  const float* emb1 = (const float*)d_in[5];
  const float* emb2 = (const float*)d_in[6];
  const float* lng  = (const float*)d_in[7];
  const float* lnb  = (const float*)d_in[8];
  const float* kW1  = (const float*)d_in[9];
  const float* kb1  = (const float*)d_in[10];
  const float* kW2  = (const float*)d_in[11];
  const float* kb2  = (const float*)d_in[12];
  const float* kW3  = (const float*)d_in[13];
  const float* kb3  = (const float*)d_in[14];
  const float* qW   = (const float*)d_in[15];
  const float* qb   = (const float*)d_in[16];
  float* out = (float*)d_out;

  // d_ws (fp8 paired fragments, uint4 units): kW1f 512KB | kW2f 1MB | kW3f 256KB | qWf 256KB
  uint4v* kW1f = (uint4v*)d_ws;
  uint4v* kW2f = kW1f + 32768;   // 4*32*4*64
  uint4v* kW3f = kW2f + 65536;   // 4*32*8*64
  uint4v* qWf  = kW3f + 16384;   // 4*8*8*64

  transform_all<<<131072 / 256, 256, 0, stream>>>(kW1, kW2, kW3, qW, kW1f, kW2f, kW3f, qWf);

  policy_main<<<4096, 1024, 0, stream>>>(be, va, ph, tr, emb0, emb1, emb2, lng, lnb,
                                         kb1, kb2, kb3, qb, kW1f, kW2f, kW3f, qWf, out);
}